// Round 1
// baseline (464.658 us; speedup 1.0000x reference)
//
#include <hip/hip_runtime.h>
#include <stdint.h>

#define DMODEL 128
#define WSZ    64
#define DFFN   256

typedef __attribute__((ext_vector_type(8))) short bf16x8;
typedef __attribute__((ext_vector_type(4))) float f32x4;

#define MFMA16(a,b,c) __builtin_amdgcn_mfma_f32_16x16x32_bf16((a),(b),(c),0,0,0)

// LDS region map (bytes), phase-reused:
#define SQK  0        // qk_in [64][128] bf16 swz   -> later sO
#define SO   0
#define SWIN 16384    // win   [64][128] bf16 swz   -> later sP (4KB/wave) & sRed
#define SPB  16384
#define SRED 16384
#define SQ   32768    // q [64][128] bf16 swz       -> later sH
#define SH   32768
#define SK   49152    // k [64][128] bf16 swz       -> later sX
#define SX   49152
#define SVT  65536    // v^T [128][64] bf16 swz
#define LDS_BYTES 81920

static __device__ __forceinline__ unsigned short f2bf(float f){
  union { float f; uint32_t u; } c; c.f = f;
  return (unsigned short)((c.u + 0x7fffu + ((c.u >> 16) & 1u)) >> 16);
}

__global__ void convert_weights(const float* __restrict__ ipw, const float* __restrict__ ow,
                                const float* __restrict__ w1, const float* __restrict__ w2,
                                unsigned short* __restrict__ wsb){
  int i = blockIdx.x*256 + threadIdx.x;
  if (i < 49152)        wsb[i] = f2bf(ipw[i]);
  else if (i < 65536)   wsb[i] = f2bf(ow[i-49152]);
  else if (i < 98304)   wsb[i] = f2bf(w1[i-65536]);
  else if (i < 131072)  wsb[i] = f2bf(w2[i-98304]);
}

__global__ __launch_bounds__(256, 2) void enc_kernel(
    const float* __restrict__ src, const float* __restrict__ pos,
    const float* __restrict__ ipb, const float* __restrict__ ob,
    const float* __restrict__ b1p, const float* __restrict__ b2p,
    const float* __restrict__ g1p, const float* __restrict__ be1p,
    const float* __restrict__ g2p, const float* __restrict__ be2p,
    const unsigned short* __restrict__ wb,
    float* __restrict__ out, int nTok)
{
  __shared__ __align__(16) char sm[LDS_BYTES];
  const int w    = blockIdx.x;
  const int tid  = threadIdx.x;
  const int lane = tid & 63;
  const int wid  = tid >> 6;
  const int l15  = lane & 15;
  const int lg   = lane >> 4;
  const f32x4  FZ = {0.f,0.f,0.f,0.f};
  const bf16x8 BZ = {0,0,0,0,0,0,0,0};

  // ---------------- P0: stage win & qk_in (bf16, swizzled) ----------------
  #pragma unroll
  for (int j = 0; j < 8; ++j) {
    int f = j*256 + tid;
    int row = f >> 5, c4 = f & 31;
    int grow = w*WSZ + row;
    float4 sv = make_float4(0.f,0.f,0.f,0.f);
    if (grow < nTok) sv = *(const float4*)(src + (size_t)grow*DMODEL + c4*4);
    float4 pv = *(const float4*)(pos + (size_t)w*WSZ*DMODEL + row*DMODEL + c4*4);
    ushort4 wv, qv;
    wv.x = f2bf(sv.x); wv.y = f2bf(sv.y); wv.z = f2bf(sv.z); wv.w = f2bf(sv.w);
    qv.x = f2bf(sv.x+pv.x); qv.y = f2bf(sv.y+pv.y); qv.z = f2bf(sv.z+pv.z); qv.w = f2bf(sv.w+pv.w);
    uint32_t a = (uint32_t)(row*256 + c4*8) ^ ((row&7)<<4);
    *(ushort4*)(sm + SWIN + a) = wv;
    *(ushort4*)(sm + SQK  + a) = qv;
  }
  __syncthreads();

  // ---------------- P1: QKV projection ----------------
  {
    f32x4 acc[6][4];
    #pragma unroll
    for (int j=0;j<6;++j){
      #pragma unroll
      for (int mt=0;mt<4;++mt) acc[j][mt] = FZ;
    }
    const int gn0 = wid*6;
    #pragma unroll
    for (int ks=0; ks<4; ++ks) {
      bf16x8 aq[4] = {BZ,BZ,BZ,BZ}, aw[4] = {BZ,BZ,BZ,BZ};
      int koff = ks*64 + lg*16;
      #pragma unroll
      for (int mt=0; mt<4; ++mt) {
        int row = mt*16 + l15;
        uint32_t a = (uint32_t)(row*256 + koff) ^ ((row&7)<<4);
        if (gn0 < 16)      aq[mt] = *(const bf16x8*)(sm + SQK  + a);
        if (gn0 + 5 >= 16) aw[mt] = *(const bf16x8*)(sm + SWIN + a);
      }
      #pragma unroll
      for (int j=0;j<6;++j) {
        int gn = gn0 + j;
        bf16x8 b = *(const bf16x8*)(wb + (size_t)(gn*16 + l15)*DMODEL + ks*32 + lg*8);
        #pragma unroll
        for (int mt=0;mt<4;++mt)
          acc[j][mt] = MFMA16((gn<16)?aq[mt]:aw[mt], b, acc[j][mt]);
      }
    }
    #pragma unroll
    for (int j=0;j<6;++j) {
      int gn = gn0 + j;
      float bias = ipb[gn*16 + l15];
      #pragma unroll
      for (int mt=0;mt<4;++mt) {
        #pragma unroll
        for (int r=0;r<4;++r) {
          unsigned short hv = f2bf(acc[j][mt][r] + bias);
          int tok = mt*16 + lg*4 + r;
          if (gn < 8) {
            int col = gn*16 + l15;
            uint32_t a = (uint32_t)(tok*256 + col*2) ^ ((tok&7)<<4);
            *(unsigned short*)(sm + SQ + a) = hv;
          } else if (gn < 16) {
            int col = (gn-8)*16 + l15;
            uint32_t a = (uint32_t)(tok*256 + col*2) ^ ((tok&7)<<4);
            *(unsigned short*)(sm + SK + a) = hv;
          } else {
            int dr = (gn-16)*16 + l15;
            uint32_t a = (uint32_t)(dr*128 + tok*2) ^ ((dr&7)<<4);
            *(unsigned short*)(sm + SVT + a) = hv;
          }
        }
      }
    }
  }
  __syncthreads();

  // ---------------- P2/P3: attention (2 heads per wave) ----------------
  {
    char* sp = sm + SPB + wid*4096;   // wave-private P buffer [32][64] bf16 swz
    #pragma unroll 1
    for (int h2=0; h2<2; ++h2) {
      const int head = wid*2 + h2;
      const int hb   = head*32;
      #pragma unroll 1
      for (int qh=0; qh<2; ++qh) {
        f32x4 s[2][4];
        #pragma unroll
        for (int qt=0;qt<2;++qt){
          #pragma unroll
          for (int kt=0;kt<4;++kt) s[qt][kt] = FZ;
        }
        bf16x8 aq[2];
        #pragma unroll
        for (int qt=0;qt<2;++qt) {
          int row = (qh*2+qt)*16 + l15;
          uint32_t a = (uint32_t)(row*256 + hb + lg*16) ^ ((row&7)<<4);
          aq[qt] = (lg < 2) ? *(const bf16x8*)(sm + SQ + a) : BZ;
        }
        #pragma unroll
        for (int kt=0;kt<4;++kt) {
          int krow = kt*16 + l15;
          uint32_t a = (uint32_t)(krow*256 + hb + lg*16) ^ ((krow&7)<<4);
          bf16x8 bk = (lg < 2) ? *(const bf16x8*)(sm + SK + a) : BZ;
          #pragma unroll
          for (int qt=0;qt<2;++qt)
            s[qt][kt] = MFMA16(aq[qt], bk, s[qt][kt]);
        }
        // softmax (row spread over 16 lanes; reduce via shfl_xor 1,2,4,8)
        float rden[2][4];
        #pragma unroll
        for (int qt=0;qt<2;++qt) {
          #pragma unroll
          for (int r=0;r<4;++r) {
            float v0 = s[qt][0][r]*0.25f, v1 = s[qt][1][r]*0.25f,
                  v2 = s[qt][2][r]*0.25f, v3 = s[qt][3][r]*0.25f;
            if (w*WSZ +  0 + l15 >= nTok) v0 = -1e30f;
            if (w*WSZ + 16 + l15 >= nTok) v1 = -1e30f;
            if (w*WSZ + 32 + l15 >= nTok) v2 = -1e30f;
            if (w*WSZ + 48 + l15 >= nTok) v3 = -1e30f;
            float m = fmaxf(fmaxf(v0,v1), fmaxf(v2,v3));
            m = fmaxf(m, __shfl_xor(m,1));
            m = fmaxf(m, __shfl_xor(m,2));
            m = fmaxf(m, __shfl_xor(m,4));
            m = fmaxf(m, __shfl_xor(m,8));
            float e0 = exp2f((v0-m)*1.442695041f);
            float e1 = exp2f((v1-m)*1.442695041f);
            float e2 = exp2f((v2-m)*1.442695041f);
            float e3 = exp2f((v3-m)*1.442695041f);
            float sum = e0+e1+e2+e3;
            sum += __shfl_xor(sum,1);
            sum += __shfl_xor(sum,2);
            sum += __shfl_xor(sum,4);
            sum += __shfl_xor(sum,8);
            rden[qt][r] = 1.f/sum;
            s[qt][0][r]=e0; s[qt][1][r]=e1; s[qt][2][r]=e2; s[qt][3][r]=e3;
          }
        }
        // P -> LDS (bf16)
        #pragma unroll
        for (int qt=0;qt<2;++qt){
          #pragma unroll
          for (int kt=0;kt<4;++kt){
            #pragma unroll
            for (int r=0;r<4;++r) {
              int qrow = qt*16 + lg*4 + r;
              uint32_t a = (uint32_t)(qrow*128 + (kt*16+l15)*2) ^ ((qrow&7)<<4);
              *(unsigned short*)(sp + a) = f2bf(s[qt][kt][r]);
            }
          }
        }
        asm volatile("s_waitcnt lgkmcnt(0)" ::: "memory");
        // PV
        f32x4 o[2]; o[0]=FZ; o[1]=FZ;
        #pragma unroll
        for (int ks=0;ks<2;++ks) {
          int vrow = head*16 + l15;
          uint32_t av = (uint32_t)(vrow*128 + ks*64 + lg*16) ^ ((vrow&7)<<4);
          bf16x8 bv = *(const bf16x8*)(sm + SVT + av);
          #pragma unroll
          for (int qt=0;qt<2;++qt) {
            int prow = qt*16 + l15;
            uint32_t ap = (uint32_t)(prow*128 + ks*64 + lg*16) ^ ((prow&7)<<4);
            bf16x8 apv = *(const bf16x8*)(sp + ap);
            o[qt] = MFMA16(apv, bv, o[qt]);
          }
        }
        #pragma unroll
        for (int qt=0;qt<2;++qt) {
          #pragma unroll
          for (int r=0;r<4;++r) {
            float val = o[qt][r] * rden[qt][r];
            int tok = qh*32 + qt*16 + lg*4 + r;
            int col = head*16 + l15;
            uint32_t a = (uint32_t)(tok*256 + col*2) ^ ((tok&7)<<4);
            *(unsigned short*)(sm + SO + a) = f2bf(val);
          }
        }
      }
    }
  }
  __syncthreads();

  // ---------------- P4: out-proj + residual + LN1 ----------------
  f32x4 xr[2][4];
  {
    f32x4 acc[2][4];
    #pragma unroll
    for (int j=0;j<2;++j){
      #pragma unroll
      for (int mt=0;mt<4;++mt) acc[j][mt] = FZ;
    }
    const unsigned short* owp = wb + 49152;
    #pragma unroll
    for (int ks=0;ks<4;++ks) {
      bf16x8 af[4];
      #pragma unroll
      for (int mt=0;mt<4;++mt) {
        int row = mt*16 + l15;
        uint32_t a = (uint32_t)(row*256 + ks*64 + lg*16) ^ ((row&7)<<4);
        af[mt] = *(const bf16x8*)(sm + SO + a);
      }
      #pragma unroll
      for (int j=0;j<2;++j) {
        int gn = wid*2 + j;
        bf16x8 b = *(const bf16x8*)(owp + (size_t)(gn*16+l15)*DMODEL + ks*32 + lg*8);
        #pragma unroll
        for (int mt=0;mt<4;++mt) acc[j][mt] = MFMA16(af[mt], b, acc[j][mt]);
      }
    }
    float* red = (float*)(sm + SRED);
    #pragma unroll
    for (int mt=0;mt<4;++mt) {
      #pragma unroll
      for (int r=0;r<4;++r) {
        int row = mt*16 + lg*4 + r;
        int grow = w*WSZ + row;
        float vsum = 0.f, vsq = 0.f;
        #pragma unroll
        for (int j=0;j<2;++j) {
          int col = wid*32 + j*16 + l15;
          float v = acc[j][mt][r] + ob[col];
          if (grow < nTok) v += src[(size_t)grow*DMODEL + col];
          acc[j][mt][r] = v;
          vsum += v; vsq += v*v;
        }
        vsum += __shfl_xor(vsum,1); vsq += __shfl_xor(vsq,1);
        vsum += __shfl_xor(vsum,2); vsq += __shfl_xor(vsq,2);
        vsum += __shfl_xor(vsum,4); vsq += __shfl_xor(vsq,4);
        vsum += __shfl_xor(vsum,8); vsq += __shfl_xor(vsq,8);
        if (l15 == 0) {
          red[(row*4 + wid)*2 + 0] = vsum;
          red[(row*4 + wid)*2 + 1] = vsq;
        }
      }
    }
    __syncthreads();
    #pragma unroll
    for (int mt=0;mt<4;++mt) {
      #pragma unroll
      for (int r=0;r<4;++r) {
        int row = mt*16 + lg*4 + r;
        float sum=0.f, sq=0.f;
        #pragma unroll
        for (int ww=0;ww<4;++ww) { sum += red[(row*4+ww)*2]; sq += red[(row*4+ww)*2+1]; }
        float mean = sum * (1.f/128.f);
        float var  = sq  * (1.f/128.f) - mean*mean;
        float rstd = rsqrtf(var + 1e-5f);
        #pragma unroll
        for (int j=0;j<2;++j) {
          int col = wid*32 + j*16 + l15;
          float xv = (acc[j][mt][r] - mean)*rstd*g1p[col] + be1p[col];
          xr[j][mt][r] = xv;
          uint32_t a = (uint32_t)(row*256 + col*2) ^ ((row&7)<<4);
          *(unsigned short*)(sm + SX + a) = f2bf(xv);
        }
      }
    }
  }
  __syncthreads();

  // ---------------- P6/P7: FFN (two hidden halves) + LN2 ----------------
  {
    f32x4 f2[2][4];
    #pragma unroll
    for (int j=0;j<2;++j){
      #pragma unroll
      for (int mt=0;mt<4;++mt) f2[j][mt] = FZ;
    }
    const unsigned short* w1p = wb + 65536;
    const unsigned short* w2p = wb + 98304;
    #pragma unroll 1
    for (int hh=0; hh<2; ++hh) {
      f32x4 a1[2][4];
      #pragma unroll
      for (int j=0;j<2;++j){
        #pragma unroll
        for (int mt=0;mt<4;++mt) a1[j][mt] = FZ;
      }
      #pragma unroll
      for (int ks=0;ks<4;++ks) {
        bf16x8 ax[4];
        #pragma unroll
        for (int mt=0;mt<4;++mt) {
          int row = mt*16 + l15;
          uint32_t a = (uint32_t)(row*256 + ks*64 + lg*16) ^ ((row&7)<<4);
          ax[mt] = *(const bf16x8*)(sm + SX + a);
        }
        #pragma unroll
        for (int j=0;j<2;++j) {
          int hcol = hh*128 + wid*32 + j*16 + l15;
          bf16x8 b = *(const bf16x8*)(w1p + (size_t)hcol*DMODEL + ks*32 + lg*8);
          #pragma unroll
          for (int mt=0;mt<4;++mt) a1[j][mt] = MFMA16(ax[mt], b, a1[j][mt]);
        }
      }
      #pragma unroll
      for (int j=0;j<2;++j) {
        int hcol = hh*128 + wid*32 + j*16 + l15;
        float bb = b1p[hcol];
        #pragma unroll
        for (int mt=0;mt<4;++mt) {
          #pragma unroll
          for (int r=0;r<4;++r) {
            float v = fmaxf(a1[j][mt][r] + bb, 0.f);
            int tok = mt*16 + lg*4 + r;
            int cl  = wid*32 + j*16 + l15;
            uint32_t a = (uint32_t)(tok*256 + cl*2) ^ ((tok&7)<<4);
            *(unsigned short*)(sm + SH + a) = f2bf(v);
          }
        }
      }
      __syncthreads();
      #pragma unroll
      for (int ks=0;ks<4;++ks) {
        bf16x8 ah[4];
        #pragma unroll
        for (int mt=0;mt<4;++mt) {
          int row = mt*16 + l15;
          uint32_t a = (uint32_t)(row*256 + ks*64 + lg*16) ^ ((row&7)<<4);
          ah[mt] = *(const bf16x8*)(sm + SH + a);
        }
        #pragma unroll
        for (int j=0;j<2;++j) {
          int gn = wid*2 + j;
          bf16x8 b = *(const bf16x8*)(w2p + (size_t)(gn*16+l15)*DFFN + hh*128 + ks*32 + lg*8);
          #pragma unroll
          for (int mt=0;mt<4;++mt) f2[j][mt] = MFMA16(ah[mt], b, f2[j][mt]);
        }
      }
      __syncthreads();
    }
    // epilogue: +b2 +x residual, LN2, store
    float* red = (float*)(sm + SRED);
    #pragma unroll
    for (int mt=0;mt<4;++mt) {
      #pragma unroll
      for (int r=0;r<4;++r) {
        int row = mt*16 + lg*4 + r;
        float vsum=0.f, vsq=0.f;
        #pragma unroll
        for (int j=0;j<2;++j) {
          int col = wid*32 + j*16 + l15;
          float v = f2[j][mt][r] + b2p[col] + xr[j][mt][r];
          f2[j][mt][r] = v;
          vsum += v; vsq += v*v;
        }
        vsum += __shfl_xor(vsum,1); vsq += __shfl_xor(vsq,1);
        vsum += __shfl_xor(vsum,2); vsq += __shfl_xor(vsq,2);
        vsum += __shfl_xor(vsum,4); vsq += __shfl_xor(vsq,4);
        vsum += __shfl_xor(vsum,8); vsq += __shfl_xor(vsq,8);
        if (l15 == 0) {
          red[(row*4 + wid)*2 + 0] = vsum;
          red[(row*4 + wid)*2 + 1] = vsq;
        }
      }
    }
    __syncthreads();
    #pragma unroll
    for (int mt=0;mt<4;++mt) {
      #pragma unroll
      for (int r=0;r<4;++r) {
        int row = mt*16 + lg*4 + r;
        int grow = w*WSZ + row;
        float sum=0.f, sq=0.f;
        #pragma unroll
        for (int ww=0;ww<4;++ww) { sum += red[(row*4+ww)*2]; sq += red[(row*4+ww)*2+1]; }
        float mean = sum * (1.f/128.f);
        float var  = sq  * (1.f/128.f) - mean*mean;
        float rstd = rsqrtf(var + 1e-5f);
        if (grow < nTok) {
          #pragma unroll
          for (int j=0;j<2;++j) {
            int col = wid*32 + j*16 + l15;
            out[(size_t)grow*DMODEL + col] = (f2[j][mt][r]-mean)*rstd*g2p[col] + be2p[col];
          }
        }
      }
    }
  }
}

extern "C" void kernel_launch(void* const* d_in, const int* in_sizes, int n_in,
                              void* d_out, int out_size, void* d_ws, size_t ws_size,
                              hipStream_t stream) {
  const float* src = (const float*)d_in[0];
  const float* pos = (const float*)d_in[1];
  // d_in[2] = inds (arange -> identity), d_in[3] = key_padding_mask (== token>=N): recomputed
  const float* ipw = (const float*)d_in[4];
  const float* ipb = (const float*)d_in[5];
  const float* ow  = (const float*)d_in[6];
  const float* ob  = (const float*)d_in[7];
  const float* w1  = (const float*)d_in[8];
  const float* b1  = (const float*)d_in[9];
  const float* w2  = (const float*)d_in[10];
  const float* b2  = (const float*)d_in[11];
  const float* g1  = (const float*)d_in[12];
  const float* be1 = (const float*)d_in[13];
  const float* g2  = (const float*)d_in[14];
  const float* be2 = (const float*)d_in[15];
  int nTok = in_sizes[0] / DMODEL;
  int nWin = in_sizes[1] / (WSZ*DMODEL);
  unsigned short* wsb = (unsigned short*)d_ws;

  hipLaunchKernelGGL(convert_weights, dim3(512), dim3(256), 0, stream, ipw, ow, w1, w2, wsb);
  hipLaunchKernelGGL(enc_kernel, dim3(nWin), dim3(256), 0, stream,
                     src, pos, ipb, ob, b1, b2, g1, be1, g2, be2, wsb,
                     (float*)d_out, nTok);
}

// Round 2
// 445.261 us; speedup vs baseline: 1.0436x; 1.0436x over previous
//
#include <hip/hip_runtime.h>
#include <stdint.h>

typedef __attribute__((ext_vector_type(8))) short bf16x8;
typedef __attribute__((ext_vector_type(4))) float f32x4;
typedef __attribute__((ext_vector_type(16))) float f32x16;

#define MFMA16(a,b,c) __builtin_amdgcn_mfma_f32_16x16x32_bf16((a),(b),(c),0,0,0)
#define MFMA32(a,b,c) __builtin_amdgcn_mfma_f32_32x32x16_bf16((a),(b),(c),0,0,0)

#define R0 0
#define R1 16384
#define R2 32768
#define LOG2E 1.442695041f

static __device__ __forceinline__ int swz16(int row, int byte){ return byte ^ ((row&15)<<4); }
static __device__ __forceinline__ int swz8 (int row, int byte){ return byte ^ ((row&7)<<4); }

static __device__ __forceinline__ uint32_t cvtpk(float lo, float hi){
  uint32_t r; asm("v_cvt_pk_bf16_f32 %0, %1, %2" : "=v"(r) : "v"(lo), "v"(hi)); return r;
}
static __device__ __forceinline__ unsigned short f2bf(float f){
  union { float f; uint32_t u; } c; c.f = f;
  return (unsigned short)((c.u + 0x7fffu + ((c.u >> 16) & 1u)) >> 16);
}
static __device__ __forceinline__ f32x16 zero16(){
  f32x16 z;
  #pragma unroll
  for (int e=0;e<16;++e) z[e]=0.f;
  return z;
}

// Assemble PV B-fragments (P^T, bf16) from swapped-QK^T score C-frag held in regs.
// s: 16 f32 e-values of one 32x32 S^T tile (lane holds q=lane&31, kk=(reg&3)+8*(reg>>2)+4*hi).
// Outputs fA (kk 0..15 window) and fB (kk 16..31 window) in 32x32x16 B-frag layout.
static __device__ __forceinline__ void packPT(const f32x16 s, int hi, bf16x8& fA, bf16x8& fB){
  uint32_t PA0=cvtpk(s[0],s[1]),  PA1=cvtpk(s[2],s[3]);
  uint32_t PB0=cvtpk(s[4],s[5]),  PB1=cvtpk(s[6],s[7]);
  uint32_t PC0=cvtpk(s[8],s[9]),  PC1=cvtpk(s[10],s[11]);
  uint32_t PD0=cvtpk(s[12],s[13]),PD1=cvtpk(s[14],s[15]);
  uint32_t x0 = __shfl_xor(hi ? PA0 : PB0, 32);
  uint32_t x1 = __shfl_xor(hi ? PA1 : PB1, 32);
  uint32_t y0 = __shfl_xor(hi ? PC0 : PD0, 32);
  uint32_t y1 = __shfl_xor(hi ? PC1 : PD1, 32);
  union { uint32_t u[4]; bf16x8 v; } ua, ub;
  ua.u[0] = hi ? x0 : PA0;  ua.u[1] = hi ? x1 : PA1;
  ua.u[2] = hi ? PB0 : x0;  ua.u[3] = hi ? PB1 : x1;
  ub.u[0] = hi ? y0 : PC0;  ub.u[1] = hi ? y1 : PC1;
  ub.u[2] = hi ? PD0 : y0;  ub.u[3] = hi ? PD1 : y1;
  fA = ua.v; fB = ub.v;
}

__global__ void convert_weights(const float* __restrict__ ipw, const float* __restrict__ ow,
                                const float* __restrict__ w1, const float* __restrict__ w2,
                                unsigned short* __restrict__ wsb){
  int i = blockIdx.x*256 + threadIdx.x;
  if (i < 49152)        wsb[i] = f2bf(ipw[i]);
  else if (i < 65536)   wsb[i] = f2bf(ow[i-49152]);
  else if (i < 98304)   wsb[i] = f2bf(w1[i-65536]);
  else if (i < 131072)  wsb[i] = f2bf(w2[i-98304]);
}

__global__ __launch_bounds__(256, 3) void enc_kernel(
    const float* __restrict__ src, const float* __restrict__ pos,
    const float* __restrict__ ipb, const float* __restrict__ ob,
    const float* __restrict__ b1p, const float* __restrict__ b2p,
    const float* __restrict__ g1p, const float* __restrict__ be1p,
    const float* __restrict__ g2p, const float* __restrict__ be2p,
    const unsigned short* __restrict__ wb,
    float* __restrict__ out, int nTok)
{
  __shared__ __align__(16) char sm[49152];
  const int blk  = blockIdx.x;
  const int tid  = threadIdx.x;
  const int lane = tid & 63;
  const int wid  = tid >> 6;
  const int l15  = lane & 15;
  const int lg   = lane >> 4;
  const int l31  = lane & 31;
  const int hi   = lane >> 5;
  const int valid = nTok - blk*64;   // >= 64 for all but the last window

  // ---------------- P0: stage win (R0) & qk (R1), wave-local rows ----------------
  #pragma unroll
  for (int j=0;j<8;++j){
    int row  = wid*16 + j*2 + hi;
    int grow = blk*64 + row;
    float4 sv = make_float4(0.f,0.f,0.f,0.f);
    if (grow < nTok) sv = *(const float4*)(src + (size_t)grow*128 + l31*4);
    float4 pv = *(const float4*)(pos + (size_t)blk*8192 + row*128 + l31*4);
    uint2 wv, qv;
    wv.x = cvtpk(sv.x, sv.y);           wv.y = cvtpk(sv.z, sv.w);
    qv.x = cvtpk(sv.x+pv.x, sv.y+pv.y); qv.y = cvtpk(sv.z+pv.z, sv.w+pv.w);
    *(uint2*)(sm + R0 + row*256 + swz16(row, l31*8)) = wv;
    *(uint2*)(sm + R1 + row*256 + swz16(row, l31*8)) = qv;
  }
  // (no barrier: each wave reads back only its own rows)

  const int myrow = wid*16 + l15;
  bf16x8 fw[4], fq[4];
  #pragma unroll
  for (int kc=0;kc<4;++kc){
    fw[kc] = *(const bf16x8*)(sm + R0 + myrow*256 + swz16(myrow, kc*64 + lg*16));
    fq[kc] = *(const bf16x8*)(sm + R1 + myrow*256 + swz16(myrow, kc*64 + lg*16));
  }

  const unsigned short* wqp = wb;
  const unsigned short* wkp = wb + 16384;
  const unsigned short* wvp = wb + 32768;

  // ---------------- P1a: V^T = Wv @ win^T  -> R2 ----------------
  #pragma unroll
  for (int Mt=0;Mt<8;++Mt){
    f32x4 acc = {0.f,0.f,0.f,0.f};
    #pragma unroll
    for (int kc=0;kc<4;++kc){
      bf16x8 a = *(const bf16x8*)(wvp + (Mt*16+l15)*128 + kc*32 + lg*8);
      acc = MFMA16(a, fw[kc], acc);
    }
    float4 b4 = *(const float4*)(ipb + 256 + Mt*16 + lg*4);
    #pragma unroll
    for (int r=0;r<4;++r){
      int d = Mt*16 + lg*4 + r;
      *(unsigned short*)(sm + R2 + d*128 + swz8(d, (wid*16+l15)*2)) = f2bf(acc[r] + b4[r? (r==1?1:(r==2?2:3)) : 0]);
    }
  }

  // ---------------- P1b: K -> R0 (over win), Q (x0.25) -> R1 in-place ----------------
  #pragma unroll
  for (int Mt=0;Mt<8;++Mt){
    f32x4 acc = {0.f,0.f,0.f,0.f};
    #pragma unroll
    for (int kc=0;kc<4;++kc){
      bf16x8 a = *(const bf16x8*)(wkp + (Mt*16+l15)*128 + kc*32 + lg*8);
      acc = MFMA16(a, fq[kc], acc);
    }
    float4 b4 = *(const float4*)(ipb + 128 + Mt*16 + lg*4);
    uint32_t p0 = cvtpk(acc[0]+b4.x, acc[1]+b4.y);
    uint32_t p1 = cvtpk(acc[2]+b4.z, acc[3]+b4.w);
    *(uint32_t*)(sm + R0 + myrow*256 + swz16(myrow, (Mt*16+lg*4)*2))   = p0;
    *(uint32_t*)(sm + R0 + myrow*256 + swz16(myrow, (Mt*16+lg*4+2)*2)) = p1;
  }
  #pragma unroll
  for (int Mt=0;Mt<8;++Mt){
    f32x4 acc = {0.f,0.f,0.f,0.f};
    #pragma unroll
    for (int kc=0;kc<4;++kc){
      bf16x8 a = *(const bf16x8*)(wqp + (Mt*16+l15)*128 + kc*32 + lg*8);
      acc = MFMA16(a, fq[kc], acc);
    }
    float4 b4 = *(const float4*)(ipb + Mt*16 + lg*4);
    uint32_t p0 = cvtpk((acc[0]+b4.x)*0.25f, (acc[1]+b4.y)*0.25f);
    uint32_t p1 = cvtpk((acc[2]+b4.z)*0.25f, (acc[3]+b4.w)*0.25f);
    *(uint32_t*)(sm + R1 + myrow*256 + swz16(myrow, (Mt*16+lg*4)*2))   = p0;
    *(uint32_t*)(sm + R1 + myrow*256 + swz16(myrow, (Mt*16+lg*4+2)*2)) = p1;
  }

  __syncthreads();   // B1: K(R0), Q(R1), V^T(R2) globally visible

  // ---------------- P2: attention, 2 heads/wave, 32x32 MFMA, P in registers ----------------
  f32x16 oacc[2][2];
  #pragma unroll
  for (int hh=0;hh<2;++hh){
    #pragma unroll
    for (int qt=0;qt<2;++qt) oacc[hh][qt] = zero16();
  }
  float rden[2][2];

  #pragma unroll
  for (int hh=0; hh<2; ++hh){
    const int head = wid*2 + hh;
    bf16x8 ka0 = *(const bf16x8*)(sm + R0 + (     l31)*256 + swz16(l31,    head*32 + hi*16));
    bf16x8 ka1 = *(const bf16x8*)(sm + R0 + (32 + l31)*256 + swz16(32+l31, head*32 + hi*16));
    #pragma unroll
    for (int qt=0; qt<2; ++qt){
      int qrow = qt*32 + l31;
      bf16x8 qb = *(const bf16x8*)(sm + R1 + qrow*256 + swz16(qrow, head*32 + hi*16));
      f32x16 s0 = MFMA32(ka0, qb, zero16());
      f32x16 s1 = MFMA32(ka1, qb, zero16());
      if (valid < 64){
        #pragma unroll
        for (int e=0;e<16;++e){
          int kk = (e&3) + 8*(e>>2) + 4*hi;
          if (kk      >= valid) s0[e] = -1e30f;
          if (kk + 32 >= valid) s1[e] = -1e30f;
        }
      }
      float m = fmaxf(s0[0], s1[0]);
      #pragma unroll
      for (int e=1;e<16;++e) m = fmaxf(m, fmaxf(s0[e], s1[e]));
      m = fmaxf(m, __shfl_xor(m, 32));
      float sum = 0.f;
      #pragma unroll
      for (int e=0;e<16;++e){ s0[e] = __builtin_amdgcn_exp2f((s0[e]-m)*LOG2E); sum += s0[e]; }
      #pragma unroll
      for (int e=0;e<16;++e){ s1[e] = __builtin_amdgcn_exp2f((s1[e]-m)*LOG2E); sum += s1[e]; }
      sum += __shfl_xor(sum, 32);
      rden[hh][qt] = __builtin_amdgcn_rcpf(sum);

      bf16x8 fr[4];
      packPT(s0, hi, fr[0], fr[1]);
      packPT(s1, hi, fr[2], fr[3]);

      #pragma unroll
      for (int kc=0;kc<4;++kc){
        int vrow = head*16 + l15;
        bf16x8 va = *(const bf16x8*)(sm + R2 + vrow*128 + swz8(vrow, kc*32 + hi*16));
        oacc[hh][qt] = MFMA32(va, fr[kc], oacc[hh][qt]);
      }
    }
  }

  __syncthreads();   // B2: all attention reads of K/Q/V^T done

  // O (normalized) -> R1 as [tok][128] bf16
  #pragma unroll
  for (int hh=0;hh<2;++hh){
    const int head = wid*2 + hh;
    #pragma unroll
    for (int qt=0;qt<2;++qt){
      int tok = qt*32 + l31;
      float rd = rden[hh][qt];
      uint32_t q0 = cvtpk(oacc[hh][qt][0]*rd, oacc[hh][qt][1]*rd);
      uint32_t q1 = cvtpk(oacc[hh][qt][2]*rd, oacc[hh][qt][3]*rd);
      uint32_t q2 = cvtpk(oacc[hh][qt][4]*rd, oacc[hh][qt][5]*rd);
      uint32_t q3 = cvtpk(oacc[hh][qt][6]*rd, oacc[hh][qt][7]*rd);
      *(uint32_t*)(sm + R1 + tok*256 + swz16(tok, (head*16 + 4*hi    )*2)) = q0;
      *(uint32_t*)(sm + R1 + tok*256 + swz16(tok, (head*16 + 4*hi + 2)*2)) = q1;
      *(uint32_t*)(sm + R1 + tok*256 + swz16(tok, (head*16 + 8 + 4*hi    )*2)) = q2;
      *(uint32_t*)(sm + R1 + tok*256 + swz16(tok, (head*16 + 8 + 4*hi + 2)*2)) = q3;
    }
  }

  __syncthreads();   // B3: O visible

  // ---------------- P3: out-proj + residual + LN1 (wave-local tokens) ----------------
  const int gtok = blk*64 + myrow;
  bf16x8 fo[4];
  #pragma unroll
  for (int kc=0;kc<4;++kc)
    fo[kc] = *(const bf16x8*)(sm + R1 + myrow*256 + swz16(myrow, kc*64 + lg*16));

  const unsigned short* wop = wb + 49152;
  f32x4 xva[8];
  {
    f32x4 op[8];
    #pragma unroll
    for (int Mt=0;Mt<8;++Mt){
      op[Mt] = (f32x4){0.f,0.f,0.f,0.f};
      #pragma unroll
      for (int kc=0;kc<4;++kc){
        bf16x8 a = *(const bf16x8*)(wop + (Mt*16+l15)*128 + kc*32 + lg*8);
        op[Mt] = MFMA16(a, fo[kc], op[Mt]);
      }
    }
    float vsum=0.f, vsq=0.f;
    #pragma unroll
    for (int Mt=0;Mt<8;++Mt){
      float4 b4 = *(const float4*)(ob + Mt*16 + lg*4);
      float2 r0 = make_float2(0.f,0.f), r1 = make_float2(0.f,0.f);
      if (gtok < nTok){
        r0 = *(const float2*)(src + (size_t)gtok*128 + Mt*16 + lg*4);
        r1 = *(const float2*)(src + (size_t)gtok*128 + Mt*16 + lg*4 + 2);
      }
      float v0 = op[Mt][0] + b4.x + r0.x;
      float v1 = op[Mt][1] + b4.y + r0.y;
      float v2 = op[Mt][2] + b4.z + r1.x;
      float v3 = op[Mt][3] + b4.w + r1.y;
      xva[Mt] = (f32x4){v0,v1,v2,v3};
      vsum += v0+v1+v2+v3;
      vsq  += v0*v0+v1*v1+v2*v2+v3*v3;
    }
    vsum += __shfl_xor(vsum,16); vsq += __shfl_xor(vsq,16);
    vsum += __shfl_xor(vsum,32); vsq += __shfl_xor(vsq,32);
    float mean = vsum*(1.f/128.f);
    float var  = vsq*(1.f/128.f) - mean*mean;
    float rstd = __builtin_amdgcn_rsqf(var + 1e-5f);
    #pragma unroll
    for (int Mt=0;Mt<8;++Mt){
      float4 g4 = *(const float4*)(g1p  + Mt*16 + lg*4);
      float4 e4 = *(const float4*)(be1p + Mt*16 + lg*4);
      float x0 = (xva[Mt][0]-mean)*rstd*g4.x + e4.x;
      float x1 = (xva[Mt][1]-mean)*rstd*g4.y + e4.y;
      float x2 = (xva[Mt][2]-mean)*rstd*g4.z + e4.z;
      float x3 = (xva[Mt][3]-mean)*rstd*g4.w + e4.w;
      xva[Mt] = (f32x4){x0,x1,x2,x3};
      *(uint32_t*)(sm + R0 + myrow*256 + swz16(myrow, (Mt*16+lg*4)*2))   = cvtpk(x0,x1);
      *(uint32_t*)(sm + R0 + myrow*256 + swz16(myrow, (Mt*16+lg*4+2)*2)) = cvtpk(x2,x3);
    }
  }

  // ---------------- P4: FFN (wave-local), h halves -> R1/R2 per-wave 4KB ----------------
  bf16x8 fx[4];
  #pragma unroll
  for (int kc=0;kc<4;++kc)
    fx[kc] = *(const bf16x8*)(sm + R0 + myrow*256 + swz16(myrow, kc*64 + lg*16));

  const unsigned short* w1p = wb + 65536;
  const unsigned short* w2p = wb + 98304;
  #pragma unroll
  for (int Mt=0;Mt<16;++Mt){
    f32x4 acc = {0.f,0.f,0.f,0.f};
    #pragma unroll
    for (int kc=0;kc<4;++kc){
      bf16x8 a = *(const bf16x8*)(w1p + (Mt*16+l15)*128 + kc*32 + lg*8);
      acc = MFMA16(a, fx[kc], acc);
    }
    float4 b4 = *(const float4*)(b1p + Mt*16 + lg*4);
    float h0 = fmaxf(acc[0]+b4.x, 0.f);
    float h1 = fmaxf(acc[1]+b4.y, 0.f);
    float h2 = fmaxf(acc[2]+b4.z, 0.f);
    float h3 = fmaxf(acc[3]+b4.w, 0.f);
    char* hb = sm + (Mt<8 ? R1 : R2) + wid*4096;
    int hl = (Mt&7)*16 + lg*4;
    *(uint32_t*)(hb + l15*256 + swz16(l15, hl*2))     = cvtpk(h0,h1);
    *(uint32_t*)(hb + l15*256 + swz16(l15, (hl+2)*2)) = cvtpk(h2,h3);
  }

  f32x4 f2a[8];
  #pragma unroll
  for (int Mt=0;Mt<8;++Mt) f2a[Mt] = (f32x4){0.f,0.f,0.f,0.f};
  #pragma unroll
  for (int kc=0;kc<8;++kc){
    char* hb = sm + (kc<4 ? R1 : R2) + wid*4096;
    bf16x8 bh = *(const bf16x8*)(hb + l15*256 + swz16(l15, (kc&3)*64 + lg*16));
    #pragma unroll
    for (int Mt=0;Mt<8;++Mt){
      bf16x8 a = *(const bf16x8*)(w2p + (Mt*16+l15)*256 + kc*32 + lg*8);
      f2a[Mt] = MFMA16(a, bh, f2a[Mt]);
    }
  }

  // epilogue: +b2 + x residual, LN2, store
  {
    float vsum=0.f, vsq=0.f;
    #pragma unroll
    for (int Mt=0;Mt<8;++Mt){
      float4 b4 = *(const float4*)(b2p + Mt*16 + lg*4);
      float v0 = f2a[Mt][0] + b4.x + xva[Mt][0];
      float v1 = f2a[Mt][1] + b4.y + xva[Mt][1];
      float v2 = f2a[Mt][2] + b4.z + xva[Mt][2];
      float v3 = f2a[Mt][3] + b4.w + xva[Mt][3];
      f2a[Mt] = (f32x4){v0,v1,v2,v3};
      vsum += v0+v1+v2+v3;
      vsq  += v0*v0+v1*v1+v2*v2+v3*v3;
    }
    vsum += __shfl_xor(vsum,16); vsq += __shfl_xor(vsq,16);
    vsum += __shfl_xor(vsum,32); vsq += __shfl_xor(vsq,32);
    float mean = vsum*(1.f/128.f);
    float var  = vsq*(1.f/128.f) - mean*mean;
    float rstd = __builtin_amdgcn_rsqf(var + 1e-5f);
    if (gtok < nTok){
      #pragma unroll
      for (int Mt=0;Mt<8;++Mt){
        float4 g4 = *(const float4*)(g2p  + Mt*16 + lg*4);
        float4 e4 = *(const float4*)(be2p + Mt*16 + lg*4);
        float o0 = (f2a[Mt][0]-mean)*rstd*g4.x + e4.x;
        float o1 = (f2a[Mt][1]-mean)*rstd*g4.y + e4.y;
        float o2 = (f2a[Mt][2]-mean)*rstd*g4.z + e4.z;
        float o3 = (f2a[Mt][3]-mean)*rstd*g4.w + e4.w;
        *(float2*)(out + (size_t)gtok*128 + Mt*16 + lg*4)     = make_float2(o0,o1);
        *(float2*)(out + (size_t)gtok*128 + Mt*16 + lg*4 + 2) = make_float2(o2,o3);
      }
    }
  }
}

extern "C" void kernel_launch(void* const* d_in, const int* in_sizes, int n_in,
                              void* d_out, int out_size, void* d_ws, size_t ws_size,
                              hipStream_t stream) {
  const float* src = (const float*)d_in[0];
  const float* pos = (const float*)d_in[1];
  // d_in[2] = inds (arange -> identity), d_in[3] = key_padding_mask (== token>=N): recomputed
  const float* ipw = (const float*)d_in[4];
  const float* ipb = (const float*)d_in[5];
  const float* ow  = (const float*)d_in[6];
  const float* ob  = (const float*)d_in[7];
  const float* w1  = (const float*)d_in[8];
  const float* b1  = (const float*)d_in[9];
  const float* w2  = (const float*)d_in[10];
  const float* b2  = (const float*)d_in[11];
  const float* g1  = (const float*)d_in[12];
  const float* be1 = (const float*)d_in[13];
  const float* g2  = (const float*)d_in[14];
  const float* be2 = (const float*)d_in[15];
  int nTok = in_sizes[0] / 128;
  int nWin = in_sizes[1] / 8192;
  unsigned short* wsb = (unsigned short*)d_ws;

  hipLaunchKernelGGL(convert_weights, dim3(512), dim3(256), 0, stream, ipw, ow, w1, w2, wsb);
  hipLaunchKernelGGL(enc_kernel, dim3(nWin), dim3(256), 0, stream,
                     src, pos, ipb, ob, b1, b2, g1, be1, g2, be2, wsb,
                     (float*)d_out, nTok);
}